// Round 6
// baseline (6191.619 us; speedup 1.0000x reference)
//
#include <hip/hip_runtime.h>

#define S 2048
#define HD 512
#define EDIM 512
#define NT 12
#define G4 2048            // 4*HD gate rows
#define NWGD 16            // workgroups per direction
#define JPW 32             // hidden units per WG (HD/NWGD)
#define HSTR 36            // hstage chunk stride in dwords (16B aligned, 2-way banks = free)

typedef unsigned short ushort_t;
typedef unsigned int uint_t;

__device__ __forceinline__ ushort_t f2b(float f) {
    uint_t u = __float_as_uint(f);
    uint_t r = u + 0x7fffu + ((u >> 16) & 1u);
    return (ushort_t)(r >> 16);
}
__device__ __forceinline__ float b2f(ushort_t h) {
    return __uint_as_float(((uint_t)h) << 16);
}
__device__ __forceinline__ float sigm(float x) { return 1.f / (1.f + __expf(-x)); }
__device__ __forceinline__ float tanh_(float x) {
    float e = __expf(2.f * x);
    return 1.f - 2.f / (e + 1.f);
}

// ---------------- xw GEMM: xw[d][t][r] = emb[tok(d,t)] . wih_d[r] + b_d[r] ----------------
__global__ __launch_bounds__(256, 2)
void xw_gemm(const int* __restrict__ sentence, const float* __restrict__ emb,
             const float* __restrict__ wih_f, const float* __restrict__ b_f,
             const float* __restrict__ wih_b, const float* __restrict__ b_b,
             ushort_t* __restrict__ xw) {
    __shared__ float As[32][68];
    __shared__ float Bs[32][68];
    __shared__ int toks[64];
    const int tid = threadIdx.x;
    const int tbase = blockIdx.x * 64;
    const int rbase = blockIdx.y * 64;
    const int dir = blockIdx.z;
    const float* wih = dir ? wih_b : wih_f;
    const float* bia = dir ? b_b : b_f;
    if (tid < 64) {
        int tt = tbase + tid;
        toks[tid] = sentence[dir ? (S - 1 - tt) : tt];
    }
    __syncthreads();
    const int lm = tid >> 2;
    const int lk = (tid & 3) * 8;
    const int ty = tid >> 4, tx = tid & 15;
    const float* aBase = emb + (size_t)toks[lm] * EDIM + lk;
    const float* bBase = wih + (size_t)(rbase + lm) * EDIM + lk;
    float acc[4][4];
#pragma unroll
    for (int i = 0; i < 4; ++i)
#pragma unroll
        for (int j = 0; j < 4; ++j) acc[i][j] = 0.f;

    for (int kc = 0; kc < EDIM; kc += 32) {
        float4 a0 = ((const float4*)(aBase + kc))[0];
        float4 a1 = ((const float4*)(aBase + kc))[1];
        float4 b0 = ((const float4*)(bBase + kc))[0];
        float4 b1 = ((const float4*)(bBase + kc))[1];
        __syncthreads();
        As[lk + 0][lm] = a0.x; As[lk + 1][lm] = a0.y; As[lk + 2][lm] = a0.z; As[lk + 3][lm] = a0.w;
        As[lk + 4][lm] = a1.x; As[lk + 5][lm] = a1.y; As[lk + 6][lm] = a1.z; As[lk + 7][lm] = a1.w;
        Bs[lk + 0][lm] = b0.x; Bs[lk + 1][lm] = b0.y; Bs[lk + 2][lm] = b0.z; Bs[lk + 3][lm] = b0.w;
        Bs[lk + 4][lm] = b1.x; Bs[lk + 5][lm] = b1.y; Bs[lk + 6][lm] = b1.z; Bs[lk + 7][lm] = b1.w;
        __syncthreads();
#pragma unroll
        for (int kk = 0; kk < 32; ++kk) {
            float4 a4 = *(const float4*)&As[kk][ty * 4];
            float4 b4 = *(const float4*)&Bs[kk][tx * 4];
            float av[4] = {a4.x, a4.y, a4.z, a4.w};
            float bv[4] = {b4.x, b4.y, b4.z, b4.w};
#pragma unroll
            for (int i = 0; i < 4; ++i)
#pragma unroll
                for (int j = 0; j < 4; ++j) acc[i][j] = fmaf(av[i], bv[j], acc[i][j]);
        }
    }
    float4 bi = *(const float4*)&bia[rbase + tx * 4];
    float bvv[4] = {bi.x, bi.y, bi.z, bi.w};
#pragma unroll
    for (int i = 0; i < 4; ++i) {
        ushort4 o;
        o.x = f2b(acc[i][0] + bvv[0]);
        o.y = f2b(acc[i][1] + bvv[1]);
        o.z = f2b(acc[i][2] + bvv[2]);
        o.w = f2b(acc[i][3] + bvv[3]);
        ushort_t* p = xw + ((size_t)dir * S + tbase + ty * 4 + i) * G4 + rbase + tx * 4;
        *(ushort4*)p = o;
    }
}

// ---------------- LSTM recurrence: 32 WGs (16/dir) x 512 threads, unit-major rows ----
// Lane layout: rg = tid>>4 (32 rowgroups = hidden units), kc = tid&15 (16 k-chunks of 32).
// Each rowgroup owns ONE hidden unit u = jbase+rg and its 4 gate rows {u, HD+u, 2HD+u, 3HD+u}.
// After the 16-lane shuffle reduce, lane kc==0 holds all 4 pre-activations for u ->
// activation is in-register: no gates[] LDS, no SYNC A (1 barrier/step).
// hstage is double-buffered so the poll (writes buf^1) can't race the matvec (reads buf).
// xw is prefetched one step ahead into registers (hides LLC/HBM latency).
__global__ __launch_bounds__(512, 1)
void lstm_rec(const float* __restrict__ whh_f, const float* __restrict__ whh_b,
              const float* __restrict__ h0, const float* __restrict__ c0,
              const ushort_t* __restrict__ xw, float* hs) {
    __shared__ float hstage[2][16 * HSTR];   // padded: chunk c at dword c*36 -> 2-way banks (free)
    const int tid = threadIdx.x;
    const int dir = blockIdx.x >> 4;
    const int wg = blockIdx.x & 15;
    const int jbase = wg * JPW;
    const int rg = tid >> 4, kc = tid & 15;
    const float* whh = dir ? whh_b : whh_f;
    const int u = jbase + rg;                 // this rowgroup's hidden unit

    // register-stationary weights: 4 gate rows (i,f,g,o) of unit u x 32 k = 32 float4
    float4 w[4][8];
#pragma unroll
    for (int g = 0; g < 4; ++g) {
        const float* wrow = whh + (size_t)(g * HD + u) * HD + kc * 32;
#pragma unroll
        for (int i = 0; i < 8; ++i) w[g][i] = *(const float4*)(wrow + i * 4);
    }

    const ushort_t* xwd = xw + (size_t)dir * S * G4;
    float* hsd = hs + (size_t)dir * S * HD;

    const bool isw = (kc == 0);
    float cj = 0.f;
    if (isw) cj = c0[dir * HD + u];

    // stage h0 (f32, padded layout) into buffer 0 — threads 0..255 cover the 512-float row
    if (tid < 256) {
        int c = tid >> 4, m = (2 * tid) & 31;
        hstage[0][c * HSTR + m] = h0[dir * HD + 2 * tid];
        hstage[0][c * HSTR + m + 1] = h0[dir * HD + 2 * tid + 1];
    }
    __syncthreads();

    // xw lookahead registers (step t values live in xr[], t+1 loads issue at loop top)
    ushort_t xr[4] = {0, 0, 0, 0};
    if (isw) {
#pragma unroll
        for (int g = 0; g < 4; ++g) xr[g] = xwd[(size_t)g * HD + u];
    }

    for (int t = 0; t < S; ++t) {
        const int pb = t & 1;
        const float* hb = hstage[pb];
        float* hw = hstage[pb ^ 1];

        ushort_t xn[4] = {0, 0, 0, 0};
        if (isw && t + 1 < S) {                 // issue next step's xw loads early
#pragma unroll
            for (int g = 0; g < 4; ++g)
                xn[g] = xwd[(size_t)(t + 1) * G4 + g * HD + u];
        }

        float a0 = 0.f, a1 = 0.f, a2 = 0.f, a3 = 0.f;
#pragma unroll
        for (int i = 0; i < 8; ++i) {
            float4 h4 = *(const float4*)&hb[kc * HSTR + i * 4];
            a0 = fmaf(w[0][i].x, h4.x, a0); a0 = fmaf(w[0][i].y, h4.y, a0);
            a0 = fmaf(w[0][i].z, h4.z, a0); a0 = fmaf(w[0][i].w, h4.w, a0);
            a1 = fmaf(w[1][i].x, h4.x, a1); a1 = fmaf(w[1][i].y, h4.y, a1);
            a1 = fmaf(w[1][i].z, h4.z, a1); a1 = fmaf(w[1][i].w, h4.w, a1);
            a2 = fmaf(w[2][i].x, h4.x, a2); a2 = fmaf(w[2][i].y, h4.y, a2);
            a2 = fmaf(w[2][i].z, h4.z, a2); a2 = fmaf(w[2][i].w, h4.w, a2);
            a3 = fmaf(w[3][i].x, h4.x, a3); a3 = fmaf(w[3][i].y, h4.y, a3);
            a3 = fmaf(w[3][i].z, h4.z, a3); a3 = fmaf(w[3][i].w, h4.w, a3);
        }
#pragma unroll
        for (int m = 1; m < 16; m <<= 1) {
            a0 += __shfl_xor(a0, m); a1 += __shfl_xor(a1, m);
            a2 += __shfl_xor(a2, m); a3 += __shfl_xor(a3, m);
        }
        if (isw) {
            // all 4 gate pre-activations for unit u are in-register: no LDS, no barrier
            float ii = sigm(a0 + b2f(xr[0]));
            float ff = sigm(a1 + b2f(xr[1]));
            float gg = tanh_(a2 + b2f(xr[2]));
            float oo = sigm(a3 + b2f(xr[3]));
            cj = ff * cj + ii * gg;
            float hnew = oo * tanh_(cj);
            __hip_atomic_store(&hsd[(size_t)t * HD + u], hnew,
                               __ATOMIC_RELAXED, __HIP_MEMORY_SCOPE_AGENT);
            xr[0] = xn[0]; xr[1] = xn[1]; xr[2] = xn[2]; xr[3] = xn[3];
        }
        if (t < S - 1 && tid < 256) {
            const unsigned long long* p0 =
                (const unsigned long long*)&hsd[(size_t)t * HD + 2 * tid];
            uint_t lo, hi;
            for (;;) {
                unsigned long long v =
                    __hip_atomic_load(p0, __ATOMIC_RELAXED, __HIP_MEMORY_SCOPE_AGENT);
                lo = (uint_t)v; hi = (uint_t)(v >> 32);
                if (lo != 0xFFFFFFFFu && hi != 0xFFFFFFFFu) break;
            }
            int c = tid >> 4, m = (2 * tid) & 31;
            hw[c * HSTR + m] = __uint_as_float(lo);
            hw[c * HSTR + m + 1] = __uint_as_float(hi);
        }
        __syncthreads();                         // single barrier per step
    }
}

// ---------------- feats: [S][12] = concat(hf, hb_rev) @ w_out.T + b_out ----------------
__global__ __launch_bounds__(256)
void feats_k(const float* __restrict__ hs, const float* __restrict__ w_out,
             const float* __restrict__ b_out, float* __restrict__ feats) {
    const int t = blockIdx.x, tid = threadIdx.x;
    float4 h4;
    if (tid < 128)
        h4 = *(const float4*)&hs[(size_t)t * HD + tid * 4];
    else
        h4 = *(const float4*)&hs[(size_t)S * HD + (size_t)(S - 1 - t) * HD + (tid - 128) * 4];
    float acc[NT];
#pragma unroll
    for (int tg = 0; tg < NT; ++tg) {
        float4 w4 = *(const float4*)&w_out[(size_t)tg * 1024 + tid * 4];
        acc[tg] = h4.x * w4.x + h4.y * w4.y + h4.z * w4.z + h4.w * w4.w;
    }
#pragma unroll
    for (int m = 1; m < 64; m <<= 1)
#pragma unroll
        for (int tg = 0; tg < NT; ++tg) acc[tg] += __shfl_xor(acc[tg], m);
    __shared__ float part[4][NT];
    if ((tid & 63) == 0) {
#pragma unroll
        for (int tg = 0; tg < NT; ++tg) part[tid >> 6][tg] = acc[tg];
    }
    __syncthreads();
    if (tid < NT)
        feats[(size_t)t * NT + tid] =
            part[0][tid] + part[1][tid] + part[2][tid] + part[3][tid] + b_out[tid];
}

// ---------------- CRF: forward algorithm + gold score, single block ----------------
__global__ __launch_bounds__(256, 1)
void crf_k(const float* __restrict__ feats, const int* __restrict__ gold,
           const float* __restrict__ trans, float* __restrict__ out) {
    extern __shared__ float sfeats[];      // S*NT floats = 96KB
    __shared__ float red[256];
    __shared__ float nprev[NT];
    __shared__ float tr[144];
    __shared__ float gold_sh;
    const int tid = threadIdx.x;
    for (int i = tid; i < S * NT / 4; i += 256)
        ((float4*)sfeats)[i] = ((const float4*)feats)[i];
    if (tid < 144) tr[tid] = trans[tid];
    __syncthreads();
    // gold score
    float gsum = 0.f;
    for (int t = tid; t < S; t += 256) {
        int a = gold[t];
        int b = t ? gold[t - 1] : 0;
        gsum += tr[a * NT + b] + sfeats[t * NT + a];
    }
    red[tid] = gsum;
    __syncthreads();
    for (int s = 128; s; s >>= 1) {
        if (tid < s) red[tid] += red[tid + s];
        __syncthreads();
    }
    if (tid == 0) gold_sh = red[0] + tr[1 * NT + gold[S - 1]];
    __syncthreads();
    // forward algorithm: i = tid/16 (next tag), j = tid%16 (prev tag)
    const int i = tid >> 4, j = tid & 15;
    const bool act = (tid < 192) && (j < NT);
    float tij = act ? tr[i * NT + j] : -3e38f;
    float prev = (j == 0) ? 0.f : -1e6f;
    for (int t = 0; t < S; ++t) {
        float v = act ? (prev + tij) : -3e38f;
        float mx = v;
        mx = fmaxf(mx, __shfl_xor(mx, 1));
        mx = fmaxf(mx, __shfl_xor(mx, 2));
        mx = fmaxf(mx, __shfl_xor(mx, 4));
        mx = fmaxf(mx, __shfl_xor(mx, 8));
        float e = __expf(v - mx);
        float ss = e;
        ss += __shfl_xor(ss, 1);
        ss += __shfl_xor(ss, 2);
        ss += __shfl_xor(ss, 4);
        ss += __shfl_xor(ss, 8);
        if (tid < 192 && j == 0) nprev[i] = mx + __logf(ss) + sfeats[t * NT + i];
        __syncthreads();
        prev = nprev[j < NT ? j : 0];
        __syncthreads();
    }
    if (tid < 64) {
        float v2 = (tid < NT) ? prev + tr[1 * NT + tid] : -3e38f;
        float mx = v2;
        mx = fmaxf(mx, __shfl_xor(mx, 1));
        mx = fmaxf(mx, __shfl_xor(mx, 2));
        mx = fmaxf(mx, __shfl_xor(mx, 4));
        mx = fmaxf(mx, __shfl_xor(mx, 8));
        float e = __expf(v2 - mx);
        float ss = e;
        ss += __shfl_xor(ss, 1);
        ss += __shfl_xor(ss, 2);
        ss += __shfl_xor(ss, 4);
        ss += __shfl_xor(ss, 8);
        if (tid == 0) out[0] = (mx + __logf(ss)) - gold_sh;
    }
}

extern "C" void kernel_launch(void* const* d_in, const int* in_sizes, int n_in,
                              void* d_out, int out_size, void* d_ws, size_t ws_size,
                              hipStream_t stream) {
    const int* sentence = (const int*)d_in[0];
    const int* gold = (const int*)d_in[1];
    const float* emb = (const float*)d_in[2];
    const float* wih_f = (const float*)d_in[3];
    const float* whh_f = (const float*)d_in[4];
    const float* b_f = (const float*)d_in[5];
    const float* wih_b = (const float*)d_in[6];
    const float* whh_b = (const float*)d_in[7];
    const float* b_b = (const float*)d_in[8];
    const float* w_out = (const float*)d_in[9];
    const float* b_out = (const float*)d_in[10];
    const float* trans = (const float*)d_in[11];
    const float* h0 = (const float*)d_in[12];
    const float* c0 = (const float*)d_in[13];
    float* out = (float*)d_out;

    char* ws = (char*)d_ws;
    const size_t XW_B = (size_t)2 * S * G4 * 2;          // 16,777,216
    const size_t HS_B = (size_t)2 * S * HD * 4;          // 8,388,608
    ushort_t* xw = (ushort_t*)ws;
    float* hs = (float*)(ws + XW_B);
    float* feats = (float*)(ws + XW_B + HS_B);

    // canary-fill h state buffer (0xFFFFFFFF, impossible output value)
    hipMemsetAsync(hs, 0xFF, HS_B, stream);

    dim3 gg(S / 64, G4 / 64, 2);
    xw_gemm<<<gg, 256, 0, stream>>>(sentence, emb, wih_f, b_f, wih_b, b_b, xw);

    lstm_rec<<<2 * NWGD, 512, 0, stream>>>(whh_f, whh_b, h0, c0, xw, hs);

    feats_k<<<S, 256, 0, stream>>>(hs, w_out, b_out, feats);

    const size_t CRF_LDS = (size_t)S * NT * 4;           // 98,304 B
    hipFuncSetAttribute((const void*)crf_k,
                        hipFuncAttributeMaxDynamicSharedMemorySize, (int)CRF_LDS);
    crf_k<<<1, 256, CRF_LDS, stream>>>(feats, gold, trans, out);
}